// Round 14
// baseline (37.719 us; speedup 1.0000x reference)
//
#include <hip/hip_runtime.h>

// ExplicitLiePE via MFMA: y[b,s] = expm(A) @ x[b,s], A = sum_k r_k * 0.5*(L_k - L_k^T).
//
// Structure = round-13 (best verified: 30.8us): 16-token groups, 4 waves/block
// row-split, inline A-fragment build (no prep kernel), dbuf LDS b-exchange,
// 1 barrier/step, 512 blocks all co-resident (2/CU, 2 waves/SIMD).
// Wall model (verified vs measurement): wall = maxM_global(~38) x ring(~1700cy);
// ring = ds_read latency + dependent-MFMA chain + VALU pack/update + barrier,
// dilated ~2x by issue-sharing with the co-resident block.
// Closed: r7/r8 duplication, r9 fat blocks, r10 no-exchange, r11 cond-renorm,
// r12 double-step Z^2 (all regressed); token-sorting (wall = max block).
//
// Round-14 ring trims:
//  1. MFMA chains 3-deep -> 18 INDEPENDENT MFMAs (separate acc per product,
//     summed on VALU in combine): removes ~2 MFMA latencies from every ring.
//  2. M margin +14 -> +12: truncation tail ~1e-4 -> ~1e-3 of scale, invisible
//     next to the 0.0156 f16-GEMM rounding floor; -2 of 38 steps.
//
// Math: G_k = (L_k - L_k^T).B, t[:,c] = sum_k (r_k[c]/rho_c) G_k[:,c]
// via v_mfma_f32_16x16x32_f16 with f16 hi/lo split of both L' and b
// (Lhi.bhi + Lhi.blo + Llo.bhi; dropped term ~2^-24). Miller backward
// recurrence generates Bessel coeffs on the fly; per-step renorm
// s = jc>1 ? rcp(jc) : 1 (result scale-invariant). Seed at m==ms, gate m<=M.
//
// Layouts:
//  - C/D: reg r of lane l = D[16*w + (l>>4)*4 + r][l&15] (HW-verified m89/m91).
//  - A/B k-slot bijection k = 8*(l>>4)+j within each K=32 tile.
//  - staging: stage[buf][hi/lo][token c][dword]; token stride 36 dwords.

typedef _Float16 half8 __attribute__((ext_vector_type(8)));
typedef __fp16 fp16x2 __attribute__((ext_vector_type(2)));
typedef float float4t __attribute__((ext_vector_type(4)));

union H2U { fp16x2 h; unsigned u; };

__device__ __forceinline__ unsigned pkrtz2(float a, float b) {
    H2U v; v.h = __builtin_amdgcn_cvt_pkrtz(a, b); return v.u;
}
__device__ __forceinline__ float h2lo(unsigned u) { H2U v; v.u = u; return (float)v.h[0]; }
__device__ __forceinline__ float h2hi(unsigned u) { H2U v; v.u = u; return (float)v.h[1]; }

// ---------------- main kernel: 4 waves per block, 16 tokens per block --------

#define PSTR 36   // token stride in dwords (b128-aligned reads)

// stage own b1 slice (hi/lo f16), sync, load full-K B fragments, flip buffer.
#define STAGE_AND_LOAD_B()                                                       \
  {                                                                              \
    unsigned h0 = pkrtz2(b1[0], b1[1]);                                          \
    unsigned h1 = pkrtz2(b1[2], b1[3]);                                          \
    unsigned l0 = pkrtz2(b1[0] - h2lo(h0), b1[1] - h2hi(h0));                    \
    unsigned l1 = pkrtz2(b1[2] - h2lo(h1), b1[3] - h2hi(h1));                    \
    const int di = 8 * w + 2 * g;                                                \
    *(uint2*)&stage[buf][0][c][di] = make_uint2(h0, h1);                         \
    *(uint2*)&stage[buf][1][c][di] = make_uint2(l0, l1);                         \
    __syncthreads();                                                             \
    _Pragma("unroll")                                                            \
    for (int kt = 0; kt < 2; ++kt) {                                             \
      Bh[kt] = *(const half8*)&stage[buf][0][c][16 * kt + 4 * g];                \
      Bl[kt] = *(const half8*)&stage[buf][1][c][16 * kt + 4 * g];                \
    }                                                                            \
    buf ^= 1;                                                                    \
  }

// 18 INDEPENDENT MFMAs (no inter-MFMA deps; separate acc per product term),
// summed on the VALU. Ring sees 1 MFMA latency instead of a 3-deep chain.
#define GEMM_COMBINE(TOUT)                                                       \
  {                                                                              \
    _Pragma("unroll")                                                            \
    for (int gen = 0; gen < 3; ++gen) {                                          \
      float q = (gen == 0) ? q0 : ((gen == 1) ? q1 : q2);                        \
      float4t hh0 = {0.f,0.f,0.f,0.f}, hh1 = {0.f,0.f,0.f,0.f};                  \
      float4t hl0 = {0.f,0.f,0.f,0.f}, hl1 = {0.f,0.f,0.f,0.f};                  \
      float4t lh0 = {0.f,0.f,0.f,0.f}, lh1 = {0.f,0.f,0.f,0.f};                  \
      hh0 = __builtin_amdgcn_mfma_f32_16x16x32_f16(Ah[gen*2+0], Bh[0], hh0, 0, 0, 0); \
      hh1 = __builtin_amdgcn_mfma_f32_16x16x32_f16(Ah[gen*2+1], Bh[1], hh1, 0, 0, 0); \
      hl0 = __builtin_amdgcn_mfma_f32_16x16x32_f16(Ah[gen*2+0], Bl[0], hl0, 0, 0, 0); \
      hl1 = __builtin_amdgcn_mfma_f32_16x16x32_f16(Ah[gen*2+1], Bl[1], hl1, 0, 0, 0); \
      lh0 = __builtin_amdgcn_mfma_f32_16x16x32_f16(Al[gen*2+0], Bh[0], lh0, 0, 0, 0); \
      lh1 = __builtin_amdgcn_mfma_f32_16x16x32_f16(Al[gen*2+1], Bh[1], lh1, 0, 0, 0); \
      _Pragma("unroll")                                                          \
      for (int r4 = 0; r4 < 4; ++r4) {                                           \
        float sum = ((hh0[r4] + hh1[r4]) + (hl0[r4] + hl1[r4]))                  \
                  + (lh0[r4] + lh1[r4]);                                         \
        if (gen == 0) TOUT[r4] = q * sum;                                        \
        else          TOUT[r4] = fmaf(q, sum, TOUT[r4]);                         \
      }                                                                          \
    }                                                                            \
  }

__global__ __launch_bounds__(256)
__attribute__((amdgpu_waves_per_eu(1, 2)))
void liepe_mfma(
    const float* __restrict__ x,
    const float* __restrict__ r_grid,
    const float* __restrict__ L_param,
    float* __restrict__ out,
    int n_tokens)
{
    __shared__ __align__(16) unsigned stage[2][2][16][PSTR];  // 18KB

    const int lane = threadIdx.x & 63;
    const int w    = threadIdx.x >> 6;   // row-slice / m2 tile, 0..3
    const int c    = lane & 15;          // token column
    const int g    = lane >> 4;          // k-group / row sub-block

    int tok = blockIdx.x * 16 + c;
    if (tok >= n_tokens) tok = n_tokens - 1;

    // A-fragments for this wave's row slice (m2 = w), built INLINE from L:
    // element (lane, j) of tile (gen, kt) = L'[16w + (lane&15)][32kt + 8g + j],
    // L' = L - L^T. 6 hi + 6 lo half8 (48 VGPRs). One-time, L2-resident.
    half8 Ah[6], Al[6];
    {
        const int i = 16 * w + (lane & 15);
        #pragma unroll
        for (int gen = 0; gen < 3; ++gen) {
            const float* Lg = L_param + gen * 4096;
            #pragma unroll
            for (int kt = 0; kt < 2; ++kt) {
                const int kk0 = 32 * kt + 8 * g;
                half8 hi, lo;
                #pragma unroll
                for (int j = 0; j < 8; ++j) {
                    int kk = kk0 + j;
                    float d = Lg[i * 64 + kk] - Lg[kk * 64 + i];
                    _Float16 h = (_Float16)d;
                    hi[j] = h;
                    lo[j] = (_Float16)(d - (float)h);
                }
                Ah[gen * 2 + kt] = hi;
                Al[gen * 2 + kt] = lo;
            }
        }
    }

    // x slice in D-layout: xv[r4] = x[tok][16w + 4g + r4].
    float xv[4];
    {
        float4 v = *(const float4*)(x + tok * 64 + 16 * w + 4 * g);
        xv[0] = v.x; xv[1] = v.y; xv[2] = v.z; xv[3] = v.w;
    }

    // Per-token scalars — computed redundantly + identically in all 4 waves.
    const float r0 = r_grid[tok * 3 + 0];
    const float r1 = r_grid[tok * 3 + 1];
    const float r2 = r_grid[tok * 3 + 2];
    const float sig2 = 0.5f * (r0 * r0 + r1 * r1 + r2 * r2);
    const float rho  = fmaf(17.3f, __builtin_sqrtf(sig2), 2.0f);
    const float inv_rho = 1.0f / rho;
    const int   M  = (int)rho + 12;     // tail ~1e-3 of scale, << f16-GEMM floor
    const int   ms = M + 10;
    const float q0 = r0 * inv_rho, q1 = r1 * inv_rho, q2 = r2 * inv_rho;

    // block max degree: wave-reduce suffices (every wave holds all 16 tokens).
    int maxM = M;
    #pragma unroll
    for (int off = 1; off < 64; off <<= 1)
        maxM = max(maxM, __shfl_xor(maxM, off));

    float jp = 0.f, jc = 0.f, N = 0.f;
    float b1[4] = {0.f, 0.f, 0.f, 0.f};
    float b2[4] = {0.f, 0.f, 0.f, 0.f};

    // ---- descent: Miller only (all b's exactly 0, no barriers needed) ----
    #pragma unroll 1
    for (int m = maxM + 10; m > maxM; --m) {
        bool sd = (m == ms);
        jc = sd ? 1e-12f : jc;
        jp = sd ? 0.f : jp;
        N  = sd ? (((m & 1) == 0) ? 2e-12f : 0.f) : N;
        float s = (jc > 1.0f) ? __builtin_amdgcn_rcpf(jc) : 1.0f;
        jc *= s; jp *= s; N *= s;
        float jm = fmaf((2.f * (float)m) * inv_rho, jc, -jp);
        jp = jc; jc = jm;
        int mm = m - 1;
        if ((mm & 1) == 0) N += (mm > 0) ? (jm + jm) : jm;
    }

    half8 Bh[2], Bl[2];
    int buf = 0;

    // ---- main fused Miller+Clenshaw loop (1 barrier per step, dbuf) ----
    #pragma unroll 1
    for (int m = maxM; m >= 1; --m) {
        bool sd = (m == ms);
        jc = sd ? 1e-12f : jc;
        jp = sd ? 0.f : jp;
        N  = sd ? (((m & 1) == 0) ? 2e-12f : 0.f) : N;

        // scale-invariant renorm: identical s in all 4 waves (same jc chain)
        float s = (jc > 1.0f) ? __builtin_amdgcn_rcpf(jc) : 1.0f;
        jc *= s; jp *= s; N *= s;
        #pragma unroll
        for (int i = 0; i < 4; ++i) { b1[i] *= s; b2[i] *= s; }

        STAGE_AND_LOAD_B();

        float t[4];
        GEMM_COMBINE(t);

        float cf = (m <= M) ? (jc + jc) : 0.f;
        #pragma unroll
        for (int i = 0; i < 4; ++i) {
            float bn = fmaf(cf, xv[i], t[i] + b2[i]);
            b2[i] = b1[i];
            b1[i] = bn;
        }

        float jm = fmaf((2.f * (float)m) * inv_rho, jc, -jp);
        jp = jc; jc = jm;
        int mm = m - 1;
        if ((mm & 1) == 0) N += (mm > 0) ? (jm + jm) : jm;
    }

    // ---- final: b0 = J0*x + (2A/rho)b1 + b2;  y = (b0 - 0.5*(2A/rho)b1)/N ----
    {
        STAGE_AND_LOAD_B();
        float t[4];
        GEMM_COMBINE(t);
        float4 v;
        float y0 = fmaf(jc, xv[0], t[0] + b2[0]);
        float y1 = fmaf(jc, xv[1], t[1] + b2[1]);
        float y2 = fmaf(jc, xv[2], t[2] + b2[2]);
        float y3 = fmaf(jc, xv[3], t[3] + b2[3]);
        v.x = (y0 - 0.5f * t[0]) / N;
        v.y = (y1 - 0.5f * t[1]) / N;
        v.z = (y2 - 0.5f * t[2]) / N;
        v.w = (y3 - 0.5f * t[3]) / N;
        *(float4*)(out + tok * 64 + 16 * w + 4 * g) = v;
    }
}

extern "C" void kernel_launch(void* const* d_in, const int* in_sizes, int n_in,
                              void* d_out, int out_size, void* d_ws, size_t ws_size,
                              hipStream_t stream) {
    const float* x = (const float*)d_in[0];
    const float* r = (const float*)d_in[1];
    const float* L = (const float*)d_in[2];
    // d_in[3] = P_sp: identity (allow_mixing=False) -> R_eff = R_r.
    float* out = (float*)d_out;

    int n_tokens = in_sizes[0] / 64;   // B*S = 8192

    int nwg = (n_tokens + 15) / 16;
    liepe_mfma<<<nwg, 256, 0, stream>>>(x, r, L, out, n_tokens);
}

// Round 15
// 29.603 us; speedup vs baseline: 1.2742x; 1.2742x over previous
//
#include <hip/hip_runtime.h>

// ExplicitLiePE via MFMA: y[b,s] = expm(A) @ x[b,s], A = sum_k r_k * 0.5*(L_k - L_k^T).
//
// Structure = round-13 (best verified: 30.8us): 16-token groups, 4 waves/block
// row-split, inline A-fragment build (no prep kernel), dbuf LDS b-exchange,
// 1 barrier/step, 512 blocks all co-resident (2/CU, 2 waves/SIMD).
// Wall model: wall = maxM_global x ring; ring = ds_read + chained MFMA +
// pack/update VALU + barrier, dilated ~2x by issue-sharing.
// Closed levers: r7/r8 duplication (46us), r9 fat blocks (37.7), r10
// no-exchange (47.5), r11 cond-renorm (33.6), r12 double-step Z^2 (55.4),
// r14 MFMA de-chaining (37.7 -- 6 accumulators = 72 inits + 60 adds/step of
// extra VALU; CDNA MFMA C-chaining has internal forwarding, chains are cheap).
//
// Round-15: exact r13 revert + keep the one safe r14 trim: M margin +14 -> +12
// (truncation tail ~1e-3 of scale, invisible under the 0.0156 f16-GEMM floor;
// -2 of ~38 wall steps).
//
// Math: G_k = (L_k - L_k^T).B, t[:,c] = sum_k (r_k[c]/rho_c) G_k[:,c]
// via v_mfma_f32_16x16x32_f16 with f16 hi/lo split of both L' and b
// (Lhi.bhi + Lhi.blo + Llo.bhi; dropped term ~2^-24). Miller backward
// recurrence generates Bessel coeffs on the fly; per-step renorm
// s = jc>1 ? rcp(jc) : 1 (result scale-invariant). Seed at m==ms, gate m<=M.
//
// Layouts:
//  - C/D: reg r of lane l = D[16*w + (l>>4)*4 + r][l&15] (HW-verified m89/m91).
//  - A/B k-slot bijection k = 8*(l>>4)+j within each K=32 tile.
//  - staging: stage[buf][hi/lo][token c][dword]; token stride 36 dwords.

typedef _Float16 half8 __attribute__((ext_vector_type(8)));
typedef __fp16 fp16x2 __attribute__((ext_vector_type(2)));
typedef float float4t __attribute__((ext_vector_type(4)));

union H2U { fp16x2 h; unsigned u; };

__device__ __forceinline__ unsigned pkrtz2(float a, float b) {
    H2U v; v.h = __builtin_amdgcn_cvt_pkrtz(a, b); return v.u;
}
__device__ __forceinline__ float h2lo(unsigned u) { H2U v; v.u = u; return (float)v.h[0]; }
__device__ __forceinline__ float h2hi(unsigned u) { H2U v; v.u = u; return (float)v.h[1]; }

// ---------------- main kernel: 4 waves per block, 16 tokens per block --------

#define PSTR 36   // token stride in dwords (b128-aligned reads)

// stage own b1 slice (hi/lo f16), sync, load full-K B fragments, flip buffer.
#define STAGE_AND_LOAD_B()                                                       \
  {                                                                              \
    unsigned h0 = pkrtz2(b1[0], b1[1]);                                          \
    unsigned h1 = pkrtz2(b1[2], b1[3]);                                          \
    unsigned l0 = pkrtz2(b1[0] - h2lo(h0), b1[1] - h2hi(h0));                    \
    unsigned l1 = pkrtz2(b1[2] - h2lo(h1), b1[3] - h2hi(h1));                    \
    const int di = 8 * w + 2 * g;                                                \
    *(uint2*)&stage[buf][0][c][di] = make_uint2(h0, h1);                         \
    *(uint2*)&stage[buf][1][c][di] = make_uint2(l0, l1);                         \
    __syncthreads();                                                             \
    _Pragma("unroll")                                                            \
    for (int kt = 0; kt < 2; ++kt) {                                             \
      Bh[kt] = *(const half8*)&stage[buf][0][c][16 * kt + 4 * g];                \
      Bl[kt] = *(const half8*)&stage[buf][1][c][16 * kt + 4 * g];                \
    }                                                                            \
    buf ^= 1;                                                                    \
  }

// 18 MFMAs for this wave's 16-row tile; kt-split accumulators (6 short chains).
#define GEMM_COMBINE(TOUT)                                                       \
  {                                                                              \
    _Pragma("unroll")                                                            \
    for (int gen = 0; gen < 3; ++gen) {                                          \
      float q = (gen == 0) ? q0 : ((gen == 1) ? q1 : q2);                        \
      float4t ac0 = {0.f, 0.f, 0.f, 0.f};                                        \
      float4t ac1 = {0.f, 0.f, 0.f, 0.f};                                        \
      ac0 = __builtin_amdgcn_mfma_f32_16x16x32_f16(Ah[gen*2+0], Bh[0], ac0, 0, 0, 0); \
      ac1 = __builtin_amdgcn_mfma_f32_16x16x32_f16(Ah[gen*2+1], Bh[1], ac1, 0, 0, 0); \
      ac0 = __builtin_amdgcn_mfma_f32_16x16x32_f16(Ah[gen*2+0], Bl[0], ac0, 0, 0, 0); \
      ac1 = __builtin_amdgcn_mfma_f32_16x16x32_f16(Ah[gen*2+1], Bl[1], ac1, 0, 0, 0); \
      ac0 = __builtin_amdgcn_mfma_f32_16x16x32_f16(Al[gen*2+0], Bh[0], ac0, 0, 0, 0); \
      ac1 = __builtin_amdgcn_mfma_f32_16x16x32_f16(Al[gen*2+1], Bh[1], ac1, 0, 0, 0); \
      _Pragma("unroll")                                                          \
      for (int r4 = 0; r4 < 4; ++r4) {                                           \
        float sum = ac0[r4] + ac1[r4];                                           \
        if (gen == 0) TOUT[r4] = q * sum;                                        \
        else          TOUT[r4] = fmaf(q, sum, TOUT[r4]);                         \
      }                                                                          \
    }                                                                            \
  }

__global__ __launch_bounds__(256) void liepe_mfma(
    const float* __restrict__ x,
    const float* __restrict__ r_grid,
    const float* __restrict__ L_param,
    float* __restrict__ out,
    int n_tokens)
{
    __shared__ __align__(16) unsigned stage[2][2][16][PSTR];  // 18KB

    const int lane = threadIdx.x & 63;
    const int w    = threadIdx.x >> 6;   // row-slice / m2 tile, 0..3
    const int c    = lane & 15;          // token column
    const int g    = lane >> 4;          // k-group / row sub-block

    int tok = blockIdx.x * 16 + c;
    if (tok >= n_tokens) tok = n_tokens - 1;

    // A-fragments for this wave's row slice (m2 = w), built INLINE from L:
    // element (lane, j) of tile (gen, kt) = L'[16w + (lane&15)][32kt + 8g + j],
    // L' = L - L^T. 6 hi + 6 lo half8 (48 VGPRs). One-time, L2-resident.
    half8 Ah[6], Al[6];
    {
        const int i = 16 * w + (lane & 15);
        #pragma unroll
        for (int gen = 0; gen < 3; ++gen) {
            const float* Lg = L_param + gen * 4096;
            #pragma unroll
            for (int kt = 0; kt < 2; ++kt) {
                const int kk0 = 32 * kt + 8 * g;
                half8 hi, lo;
                #pragma unroll
                for (int j = 0; j < 8; ++j) {
                    int kk = kk0 + j;
                    float d = Lg[i * 64 + kk] - Lg[kk * 64 + i];
                    _Float16 h = (_Float16)d;
                    hi[j] = h;
                    lo[j] = (_Float16)(d - (float)h);
                }
                Ah[gen * 2 + kt] = hi;
                Al[gen * 2 + kt] = lo;
            }
        }
    }

    // x slice in D-layout: xv[r4] = x[tok][16w + 4g + r4].
    float xv[4];
    {
        float4 v = *(const float4*)(x + tok * 64 + 16 * w + 4 * g);
        xv[0] = v.x; xv[1] = v.y; xv[2] = v.z; xv[3] = v.w;
    }

    // Per-token scalars — computed redundantly + identically in all 4 waves.
    const float r0 = r_grid[tok * 3 + 0];
    const float r1 = r_grid[tok * 3 + 1];
    const float r2 = r_grid[tok * 3 + 2];
    const float sig2 = 0.5f * (r0 * r0 + r1 * r1 + r2 * r2);
    const float rho  = fmaf(17.3f, __builtin_sqrtf(sig2), 2.0f);
    const float inv_rho = 1.0f / rho;
    const int   M  = (int)rho + 12;     // tail ~1e-3 of scale, << f16-GEMM floor
    const int   ms = M + 10;
    const float q0 = r0 * inv_rho, q1 = r1 * inv_rho, q2 = r2 * inv_rho;

    // block max degree: wave-reduce suffices (every wave holds all 16 tokens).
    int maxM = M;
    #pragma unroll
    for (int off = 1; off < 64; off <<= 1)
        maxM = max(maxM, __shfl_xor(maxM, off));

    float jp = 0.f, jc = 0.f, N = 0.f;
    float b1[4] = {0.f, 0.f, 0.f, 0.f};
    float b2[4] = {0.f, 0.f, 0.f, 0.f};

    // ---- descent: Miller only (all b's exactly 0, no barriers needed) ----
    #pragma unroll 1
    for (int m = maxM + 10; m > maxM; --m) {
        bool sd = (m == ms);
        jc = sd ? 1e-12f : jc;
        jp = sd ? 0.f : jp;
        N  = sd ? (((m & 1) == 0) ? 2e-12f : 0.f) : N;
        float s = (jc > 1.0f) ? __builtin_amdgcn_rcpf(jc) : 1.0f;
        jc *= s; jp *= s; N *= s;
        float jm = fmaf((2.f * (float)m) * inv_rho, jc, -jp);
        jp = jc; jc = jm;
        int mm = m - 1;
        if ((mm & 1) == 0) N += (mm > 0) ? (jm + jm) : jm;
    }

    half8 Bh[2], Bl[2];
    int buf = 0;

    // ---- main fused Miller+Clenshaw loop (1 barrier per step, dbuf) ----
    #pragma unroll 1
    for (int m = maxM; m >= 1; --m) {
        bool sd = (m == ms);
        jc = sd ? 1e-12f : jc;
        jp = sd ? 0.f : jp;
        N  = sd ? (((m & 1) == 0) ? 2e-12f : 0.f) : N;

        // scale-invariant renorm: identical s in all 4 waves (same jc chain)
        float s = (jc > 1.0f) ? __builtin_amdgcn_rcpf(jc) : 1.0f;
        jc *= s; jp *= s; N *= s;
        #pragma unroll
        for (int i = 0; i < 4; ++i) { b1[i] *= s; b2[i] *= s; }

        STAGE_AND_LOAD_B();

        float t[4];
        GEMM_COMBINE(t);

        float cf = (m <= M) ? (jc + jc) : 0.f;
        #pragma unroll
        for (int i = 0; i < 4; ++i) {
            float bn = fmaf(cf, xv[i], t[i] + b2[i]);
            b2[i] = b1[i];
            b1[i] = bn;
        }

        float jm = fmaf((2.f * (float)m) * inv_rho, jc, -jp);
        jp = jc; jc = jm;
        int mm = m - 1;
        if ((mm & 1) == 0) N += (mm > 0) ? (jm + jm) : jm;
    }

    // ---- final: b0 = J0*x + (2A/rho)b1 + b2;  y = (b0 - 0.5*(2A/rho)b1)/N ----
    {
        STAGE_AND_LOAD_B();
        float t[4];
        GEMM_COMBINE(t);
        float4 v;
        float y0 = fmaf(jc, xv[0], t[0] + b2[0]);
        float y1 = fmaf(jc, xv[1], t[1] + b2[1]);
        float y2 = fmaf(jc, xv[2], t[2] + b2[2]);
        float y3 = fmaf(jc, xv[3], t[3] + b2[3]);
        v.x = (y0 - 0.5f * t[0]) / N;
        v.y = (y1 - 0.5f * t[1]) / N;
        v.z = (y2 - 0.5f * t[2]) / N;
        v.w = (y3 - 0.5f * t[3]) / N;
        *(float4*)(out + tok * 64 + 16 * w + 4 * g) = v;
    }
}

extern "C" void kernel_launch(void* const* d_in, const int* in_sizes, int n_in,
                              void* d_out, int out_size, void* d_ws, size_t ws_size,
                              hipStream_t stream) {
    const float* x = (const float*)d_in[0];
    const float* r = (const float*)d_in[1];
    const float* L = (const float*)d_in[2];
    // d_in[3] = P_sp: identity (allow_mixing=False) -> R_eff = R_r.
    float* out = (float*)d_out;

    int n_tokens = in_sizes[0] / 64;   // B*S = 8192

    int nwg = (n_tokens + 15) / 16;
    liepe_mfma<<<nwg, 256, 0, stream>>>(x, r, L, out, n_tokens);
}